// Round 10
// baseline (181.558 us; speedup 1.0000x reference)
//
#include <hip/hip_runtime.h>

// FCPlanenet on MI355X (gfx950). fp32 inputs, fp32 output [32*9].
// Round 10: swapped-operand MFMA. Since A-frag and B-frag lane maps are
// identical (lane&15 = own index, k=(lane>>4)*8+j), compute
//   D = mfma(A=Wt-frag (W[k][m]), B=h-frag (h[n][k])) = h_next^T tiles:
//   lane holds rows-of-D = 4 consecutive FEATURES (m = nt*16 + g*4 + reg),
//   col = point-row (n = c). One f32x4 acc = one 8B ushort4 slot of the
//   frag-order h layout -> NO LDS transpose at all. pm via shfl_xor(1,2,4,8).
// h layout (verified R6-R9): block owns 4096 u16x8 slots;
//   slot[tl*256 + ks*64 + 16*g' + c] = row tl*16+c, features ks*32+g'*8..+7.
// Store mapping (derived): acc[mi][nt] -> slot[(w*2+mi)*256 + (nt>>1)*64 +
//   ((nt&1)*2 + (g>>1))*16 + c], u16 offset (g&1)*4.

using bf16x8 = __attribute__((ext_vector_type(8))) __bf16;
using u16x8  = __attribute__((ext_vector_type(8))) unsigned short;
using f32x4  = __attribute__((ext_vector_type(4))) float;

__device__ __forceinline__ unsigned short f2bf(float x) {
  __bf16 b = (__bf16)x;
  return __builtin_bit_cast(unsigned short, b);
}

__device__ __forceinline__ f32x4 mfma16(bf16x8 a, bf16x8 b, f32x4 c) {
  return __builtin_amdgcn_mfma_f32_16x16x32_bf16(a, b, c, 0, 0, 0);
}

union FragU { unsigned short us[8]; u16x8 u; bf16x8 v; };

// ---------------------------------------------------------------------------
// Pack all four W (fp32 KxN, N=128) -> frag-ordered bf16 into one buffer.
// slot = (ks*8 + nt)*64 + lane ; holds W[ks*32+(lane>>4)*8+j][nt*16+(lane&15)]
// ---------------------------------------------------------------------------
__global__ __launch_bounds__(256) void k_pack_all(
    const float* __restrict__ W0, const float* __restrict__ W1,
    const float* __restrict__ W2, const float* __restrict__ W3,
    unsigned short* __restrict__ Wt) {
  const int blk = blockIdx.x, t = threadIdx.x;
  const float* src; int slot; unsigned short* dst;
  if (blk < 16)      { src = W0; slot = blk * 256 + t;        dst = Wt; }
  else if (blk < 24) { src = W1; slot = (blk - 16) * 256 + t; dst = Wt + 32768; }
  else if (blk < 32) { src = W2; slot = (blk - 24) * 256 + t; dst = Wt + 49152; }
  else               { src = W3; slot = (blk - 32) * 256 + t; dst = Wt + 65536; }
  const int ks = slot >> 9, rem = slot & 511;
  const int nt = rem >> 6, lane = rem & 63;
  const int n = nt * 16 + (lane & 15);
  const int kb = ks * 32 + ((lane >> 4) << 3);
  FragU fr;
#pragma unroll
  for (int j = 0; j < 8; ++j) fr.us[j] = f2bf(src[(kb + j) * 128 + n]);
  reinterpret_cast<u16x8*>(dst)[slot] = fr.u;
}

// ---------------------------------------------------------------------------
// Register-direct epilogue (swapped layout): per nt, bias+relu, 8B h-store,
// per-feature max via shfl_xor over the 16-lane row dim.
// ---------------------------------------------------------------------------
__device__ __forceinline__ void epilogue_swapped(
    float (*pmaxs)[128], const f32x4 (&acc)[2][8],
    const float* __restrict__ biasvec, int t, int blk,
    unsigned short* __restrict__ h, float* __restrict__ pm, bool write_h) {
  const int w = t >> 6, lane = t & 63, g = lane >> 4, c = lane & 15;
  unsigned short* hblk = h + (size_t)blk * 32768;
#pragma unroll
  for (int nt = 0; nt < 8; ++nt) {
    const float4 bb = *reinterpret_cast<const float4*>(&biasvec[nt * 16 + g * 4]);
    float vm[4] = {0.f, 0.f, 0.f, 0.f};
#pragma unroll
    for (int mi = 0; mi < 2; ++mi) {
      const float v0 = fmaxf(acc[mi][nt][0] + bb.x, 0.f);
      const float v1 = fmaxf(acc[mi][nt][1] + bb.y, 0.f);
      const float v2 = fmaxf(acc[mi][nt][2] + bb.z, 0.f);
      const float v3 = fmaxf(acc[mi][nt][3] + bb.w, 0.f);
      vm[0] = fmaxf(vm[0], v0); vm[1] = fmaxf(vm[1], v1);
      vm[2] = fmaxf(vm[2], v2); vm[3] = fmaxf(vm[3], v3);
      if (write_h) {
        ushort4 s4;
        s4.x = f2bf(v0); s4.y = f2bf(v1); s4.z = f2bf(v2); s4.w = f2bf(v3);
        const int slot = (w * 2 + mi) * 256 + (nt >> 1) * 64 +
                         ((nt & 1) * 2 + (g >> 1)) * 16 + c;
        *reinterpret_cast<ushort4*>(&hblk[slot * 8 + (g & 1) * 4]) = s4;
      }
    }
#pragma unroll
    for (int r = 0; r < 4; ++r) {
      vm[r] = fmaxf(vm[r], __shfl_xor(vm[r], 1, 64));
      vm[r] = fmaxf(vm[r], __shfl_xor(vm[r], 2, 64));
      vm[r] = fmaxf(vm[r], __shfl_xor(vm[r], 4, 64));
      vm[r] = fmaxf(vm[r], __shfl_xor(vm[r], 8, 64));
    }
    if (c == 0) {
#pragma unroll
      for (int r = 0; r < 4; ++r) pmaxs[w][nt * 16 + g * 4 + r] = vm[r];
    }
  }
  __syncthreads();
  if (t < 128) {
    float m = pmaxs[0][t];
#pragma unroll
    for (int i = 1; i < 8; ++i) m = fmaxf(m, pmaxs[i][t]);
    pm[(size_t)blk * 128 + t] = m;
  }
}

// ---------------------------------------------------------------------------
// Layer 0: h = relu( relu(p@Wpos+bpos) @ W0 + b0 ), 256 rows/block, 8 waves.
// ---------------------------------------------------------------------------
__global__ __launch_bounds__(512, 4) void k_layer0(
    const float* __restrict__ p, const float* __restrict__ Wpos,
    const float* __restrict__ bpos, const float* __restrict__ b0,
    const unsigned short* __restrict__ Wt0, unsigned short* __restrict__ h,
    float* __restrict__ pm) {
  __shared__ float wls[1024];      // Wpos (3x256) + bpos
  __shared__ float pmaxs[8][128];
  const int t = threadIdx.x, blk = blockIdx.x;
  for (int i = t; i < 1024; i += 512) wls[i] = (i < 768) ? Wpos[i] : bpos[i - 768];

  const int w = t >> 6, lane = t & 63, g = lane >> 4, c = lane & 15;
  float px[2], py[2], pz[2];
#pragma unroll
  for (int mi = 0; mi < 2; ++mi) {
    const int row = blk * 256 + (w * 2 + mi) * 16 + c;
    px[mi] = p[row * 3 + 0]; py[mi] = p[row * 3 + 1]; pz[mi] = p[row * 3 + 2];
  }

  f32x4 acc[2][8];
#pragma unroll
  for (int mi = 0; mi < 2; ++mi)
#pragma unroll
    for (int nt = 0; nt < 8; ++nt) acc[mi][nt] = f32x4{0.f, 0.f, 0.f, 0.f};
  __syncthreads();

  const bf16x8* Bf = reinterpret_cast<const bf16x8*>(Wt0);
#pragma unroll
  for (int ks = 0; ks < 8; ++ks) {
    FragU a[2];
    const int kb = ks * 32 + g * 8;
#pragma unroll
    for (int mi = 0; mi < 2; ++mi) {
#pragma unroll
      for (int half = 0; half < 2; ++half) {
        const int kq = kb + half * 4;
        const float4 w0 = *reinterpret_cast<const float4*>(&wls[kq]);
        const float4 w1 = *reinterpret_cast<const float4*>(&wls[256 + kq]);
        const float4 w2 = *reinterpret_cast<const float4*>(&wls[512 + kq]);
        const float4 bb = *reinterpret_cast<const float4*>(&wls[768 + kq]);
        a[mi].us[half * 4 + 0] = f2bf(fmaxf(bb.x + px[mi] * w0.x + py[mi] * w1.x + pz[mi] * w2.x, 0.f));
        a[mi].us[half * 4 + 1] = f2bf(fmaxf(bb.y + px[mi] * w0.y + py[mi] * w1.y + pz[mi] * w2.y, 0.f));
        a[mi].us[half * 4 + 2] = f2bf(fmaxf(bb.z + px[mi] * w0.z + py[mi] * w1.z + pz[mi] * w2.z, 0.f));
        a[mi].us[half * 4 + 3] = f2bf(fmaxf(bb.w + px[mi] * w0.w + py[mi] * w1.w + pz[mi] * w2.w, 0.f));
      }
    }
#pragma unroll
    for (int nt = 0; nt < 8; ++nt) {
      const bf16x8 Wf = Bf[(ks * 8 + nt) * 64 + lane];
      acc[0][nt] = mfma16(Wf, a[0].v, acc[0][nt]);   // swapped operands
      acc[1][nt] = mfma16(Wf, a[1].v, acc[1][nt]);
    }
  }
  epilogue_swapped(pmaxs, acc, b0, t, blk, h, pm, true);
}

// ---------------------------------------------------------------------------
// Pooled layer: h = relu( h @ Wa + c[b] ), 256 rows/block, 8 waves, in-place.
// ---------------------------------------------------------------------------
__global__ __launch_bounds__(512, 4) void k_layer(
    const unsigned short* __restrict__ Wta, const float* __restrict__ cvec,
    unsigned short* __restrict__ h, float* __restrict__ pm, int write_h) {
  __shared__ float pmaxs[8][128];
  const int t = threadIdx.x, blk = blockIdx.x;
  const int w = t >> 6, lane = t & 63;
  const int b = blk >> 5;   // 32 blocks (of 256 rows) per batch of 8192

  f32x4 acc[2][8];
#pragma unroll
  for (int mi = 0; mi < 2; ++mi)
#pragma unroll
    for (int nt = 0; nt < 8; ++nt) acc[mi][nt] = f32x4{0.f, 0.f, 0.f, 0.f};

  const u16x8* hbase = reinterpret_cast<const u16x8*>(h) + (size_t)blk * 4096;
  const bf16x8* Bf = reinterpret_cast<const bf16x8*>(Wta);
#pragma unroll
  for (int ks = 0; ks < 4; ++ks) {
    FragU a0, a1;
    a0.u = hbase[(w * 2 + 0) * 256 + ks * 64 + lane];
    a1.u = hbase[(w * 2 + 1) * 256 + ks * 64 + lane];
#pragma unroll
    for (int nt = 0; nt < 8; ++nt) {
      const bf16x8 Wf = Bf[(ks * 8 + nt) * 64 + lane];
      acc[0][nt] = mfma16(Wf, a0.v, acc[0][nt]);     // swapped operands
      acc[1][nt] = mfma16(Wf, a1.v, acc[1][nt]);
    }
  }
  epilogue_swapped(pmaxs, acc, cvec + b * 128, t, blk, h, pm, write_h != 0);
}

// ---------------------------------------------------------------------------
// Combine: m[b] = max over 32 partials; c[b][n] = relu(m)@Wn[128:256] + bn
// ---------------------------------------------------------------------------
__global__ __launch_bounds__(256) void k_combine(
    const float* __restrict__ pm, const float* __restrict__ Wn,
    const float* __restrict__ bn, float* __restrict__ cout) {
  const int b = blockIdx.x, t = threadIdx.x;
  const int f = t & 127, half = t >> 7;
  __shared__ float part[2][128];
  __shared__ float rm[128];
  float m = 0.f;
  for (int i = half * 16; i < half * 16 + 16; ++i)
    m = fmaxf(m, pm[(size_t)(b * 32 + i) * 128 + f]);
  part[half][f] = m;
  __syncthreads();
  if (t < 128) rm[f] = fmaxf(part[0][f], part[1][f]);
  __syncthreads();
  float s = 0.f;
  for (int q = half * 64; q < half * 64 + 64; ++q)
    s += rm[q] * Wn[(128 + q) * 128 + f];
  part[half][f] = s;
  __syncthreads();
  if (t < 128) cout[b * 128 + f] = part[0][f] + part[1][f] + bn[f];
}

// ---------------------------------------------------------------------------
// Final: g = max over 32 partials; 5-layer head MLP (fp32); out fp32 [32,9]
// ---------------------------------------------------------------------------
__global__ __launch_bounds__(256) void k_final(
    const float* __restrict__ pm3,
    const float* __restrict__ Wc,  const float* __restrict__ bc,
    const float* __restrict__ Wm0, const float* __restrict__ bm0,
    const float* __restrict__ Wm1, const float* __restrict__ bm1,
    const float* __restrict__ Wm2, const float* __restrict__ bm2,
    const float* __restrict__ Wp,  const float* __restrict__ bp,
    float* __restrict__ out) {
  const int b = blockIdx.x, t = threadIdx.x;
  const int f = t & 127, half = t >> 7;
  __shared__ float part[2][128];
  __shared__ float x[128];
  float m = 0.f;
  for (int i = half * 16; i < half * 16 + 16; ++i)
    m = fmaxf(m, pm3[(size_t)(b * 32 + i) * 128 + f]);
  part[half][f] = m;
  __syncthreads();
  if (t < 128) x[f] = fmaxf(part[0][f], part[1][f]);
  __syncthreads();

  const float* Ws[4] = {Wc, Wm0, Wm1, Wm2};
  const float* bs[4] = {bc, bm0, bm1, bm2};
#pragma unroll
  for (int L = 0; L < 4; ++L) {
    float s = 0.f;
    for (int q = half * 64; q < half * 64 + 64; ++q)
      s += x[q] * Ws[L][q * 128 + f];
    part[half][f] = s;
    __syncthreads();
    if (t < 128) x[f] = fmaxf(part[0][f] + part[1][f] + bs[L][f], 0.f);
    __syncthreads();
  }
  if (t < 9) {
    float s = bp[t];
    for (int q = 0; q < 128; ++q) s += x[q] * Wp[q * 9 + t];
    out[b * 9 + t] = s;
  }
}

// ---------------------------------------------------------------------------
extern "C" void kernel_launch(void* const* d_in, const int* in_sizes, int n_in,
                              void* d_out, int out_size, void* d_ws, size_t ws_size,
                              hipStream_t stream) {
  const float *p = nullptr, *Wpos = nullptr, *bpos = nullptr;
  const float *Wp = nullptr, *bp = nullptr;
  const float *W256[4] = {}; int nW256 = 0;
  const float *W128[4] = {}; int nW128 = 0;
  const float *B128[8] = {}; int nB128 = 0;
  for (int i = 0; i < n_in; ++i) {
    const float* q = (const float*)d_in[i];
    switch (in_sizes[i]) {
      case 786432: p = q; break;
      case 768:    Wpos = q; break;
      case 256:    bpos = q; break;
      case 1152:   Wp = q; break;
      case 9:      bp = q; break;
      case 32768:  if (nW256 < 4) W256[nW256++] = q; break;
      case 16384:  if (nW128 < 4) W128[nW128++] = q; break;
      case 128:    if (nB128 < 8) B128[nB128++] = q; break;
      default: break;
    }
  }
  const float *W0 = W256[0], *W1 = W256[1], *W2 = W256[2], *W3 = W256[3];
  const float *Wc = W128[0], *Wm0 = W128[1], *Wm1 = W128[2], *Wm2 = W128[3];
  const float *b0 = B128[0], *b1 = B128[1], *b2 = B128[2], *b3 = B128[3];
  const float *bc = B128[4], *bm0 = B128[5], *bm1 = B128[6], *bm2 = B128[7];
  float* out = (float*)d_out;

  // ws layout (~65 MB)
  char* ws = (char*)d_ws;
  float* pm = (float*)ws;                                        // 512 KiB
  float* cv = (float*)(ws + 524288);                             // 16 KiB
  unsigned short* Wt = (unsigned short*)(ws + 524288 + 16384);   // 160 KiB
  unsigned short* Wt0 = Wt;
  unsigned short* Wt1 = Wt + 32768;
  unsigned short* Wt2 = Wt + 49152;
  unsigned short* Wt3 = Wt + 65536;
  unsigned short* h = Wt + 81920;                                // 64 MiB

  k_pack_all<<<40, 256, 0, stream>>>(W0, W1, W2, W3, Wt);
  k_layer0<<<1024, 512, 0, stream>>>(p, Wpos, bpos, b0, Wt0, h, pm);
  k_combine<<<32, 256, 0, stream>>>(pm, W1, b1, cv);
  k_layer<<<1024, 512, 0, stream>>>(Wt1, cv, h, pm, 1);
  k_combine<<<32, 256, 0, stream>>>(pm, W2, b2, cv);
  k_layer<<<1024, 512, 0, stream>>>(Wt2, cv, h, pm, 1);
  k_combine<<<32, 256, 0, stream>>>(pm, W3, b3, cv);
  k_layer<<<1024, 512, 0, stream>>>(Wt3, cv, h, pm, 0);
  k_final<<<32, 256, 0, stream>>>(pm, Wc, bc, Wm0, bm0, Wm1, bm1, Wm2, bm2, Wp, bp, out);
}